// Round 2
// baseline (135.069 us; speedup 1.0000x reference)
//
#include <hip/hip_runtime.h>

// YOLO v1 loss, fused single-pass reduction — coalesced-staging version.
// Shapes: output/target (8192, 7, 7, 30) f32, grid_mask_obj (8192,7,7) i32.
// Out: scalar f32 loss.
//
// Strategy: per 256-thread block = 256 cells.
//  - Stream both inputs fully coalesced (float2, 8 B/lane; thread tid reads
//    float2 index tid+256*k, k=0..14 -> dense 512 B per wave-instruction).
//  - Channels 10..29 (cls term) are a masked elementwise SSE: folded into a
//    register accumulator during the stream, never staged.
//  - Channels 0..9 (boxes+conf) staged to LDS with stride 11 (10 + 1 pad;
//    gcd(11,32)=1 -> conflict-free reads), then per-cell IoU/selection math.
//  - LDS = 2*256*11*4 + 1KB mask ~= 23.5 KB -> 6 blocks/CU, 24 waves/CU.

constexpr float CELLW_  = 1.0f / 7.0f;
constexpr float IMG_    = 448.0f;
constexpr float INV_BS_ = 1.0f / 8192.0f;

__global__ __launch_bounds__(256) void yolo_loss_kernel(
    const float* __restrict__ outp, const float* __restrict__ tgtp,
    const int* __restrict__ maskp, float* __restrict__ res)
{
    __shared__ int   lmask[256];
    __shared__ float lo[256 * 11];
    __shared__ float lt[256 * 11];

    const int tid   = threadIdx.x;
    const int cell0 = blockIdx.x * 256;   // grid is exact: 401408 = 1568*256

    lmask[tid] = maskp[cell0 + tid];
    __syncthreads();                      // mask visible to all waves

    const float2* po = reinterpret_cast<const float2*>(outp) + (size_t)cell0 * 15;
    const float2* pt = reinterpret_cast<const float2*>(tgtp) + (size_t)cell0 * 15;

    float acc = 0.0f;

    // Incremental (cell c, channel ch) for dword index d0 = 2*tid + 512*k.
    // Step 512 dwords = 17 cells + 2 channels.
    int c  = (2 * tid) / 30;
    int ch = (2 * tid) - c * 30;          // always even

#pragma unroll
    for (int k = 0; k < 15; ++k) {
        const int j = tid + 256 * k;
        float2 vo = po[j];
        float2 vt = pt[j];
        if (ch < 10) {
            // box/conf channels -> LDS (pair never straddles ch=9/10: ch even)
            lo[c * 11 + ch]     = vo.x;
            lo[c * 11 + ch + 1] = vo.y;
            lt[c * 11 + ch]     = vt.x;
            lt[c * 11 + ch + 1] = vt.y;
        } else {
            // cls channels: obj-masked SSE, accumulate in-register
            float dx = vo.x - vt.x;
            float dy = vo.y - vt.y;
            float add = dx * dx + dy * dy;
            acc += lmask[c] ? add : 0.0f;
        }
        ch += 2; c += 17;
        if (ch >= 30) { ch -= 30; c += 1; }
    }
    __syncthreads();

    // ---- per-cell box math (thread tid owns cell cell0+tid) ----
    {
        const float* o = &lo[tid * 11];
        const float* t = &lt[tid * 11];
        const int    m = lmask[tid];

        const int rem = (cell0 + tid) % 49;  // row = rem/7 (y), col = rem%7 (x)
        const float gx = (float)(rem % 7) * CELLW_;
        const float gy = (float)(rem / 7) * CELLW_;

        // target box 0 -> pixel corners
        const float tx = (t[0] * CELLW_ + gx) * IMG_;
        const float ty = (t[1] * CELLW_ + gy) * IMG_;
        const float tw = t[2] * IMG_, th = t[3] * IMG_;
        const float tx1 = tx - tw * 0.5f, tx2 = tx + tw * 0.5f;
        const float ty1 = ty - th * 0.5f, ty2 = ty + th * 0.5f;
        const float area_t = (tx2 - tx1) * (ty2 - ty1);

        float iou[2];
#pragma unroll
        for (int b = 0; b < 2; ++b) {
            float b0 = (b == 0) ? o[0] : o[5];
            float b1 = (b == 0) ? o[1] : o[6];
            float b2 = (b == 0) ? o[2] : o[7];
            float b3 = (b == 0) ? o[3] : o[8];
            float x = (b0 * CELLW_ + gx) * IMG_;
            float y = (b1 * CELLW_ + gy) * IMG_;
            float w = b2 * IMG_, h = b3 * IMG_;
            float x1 = x - w * 0.5f, x2 = x + w * 0.5f;
            float y1 = y - h * 0.5f, y2 = y + h * 0.5f;
            float iw = fmaxf(fminf(x2, tx2) - fmaxf(x1, tx1), 0.0f);
            float ih = fmaxf(fminf(y2, ty2) - fmaxf(y1, ty1), 0.0f);
            float inter = iw * ih;
            float area_o = (x2 - x1) * (y2 - y1);
            iou[b] = inter / (area_o + area_t - inter);
        }

        const int   max_id  = (iou[1] > iou[0]) ? 1 : 0;   // argmax, tie->first
        const float max_iou = fmaxf(iou[0], iou[1]);

        // selected box (static indices via ternaries — no runtime indexing)
        const float so0 = max_id ? o[5] : o[0];
        const float so1 = max_id ? o[6] : o[1];
        const float so2 = max_id ? o[7] : o[2];
        const float so3 = max_id ? o[8] : o[3];
        const float st0 = max_id ? t[5] : t[0];
        const float st1 = max_id ? t[6] : t[1];
        const float st2 = max_id ? t[7] : t[2];
        const float st3 = max_id ? t[8] : t[3];

        const float dxy0 = so0 - st0, dxy1 = so1 - st1;
        const float xy_loss = dxy0 * dxy0 + dxy1 * dxy1;

        const float dwh0 = sqrtf(so2) - sqrtf(st2);
        const float dwh1 = sqrtf(so3) - sqrtf(st3);
        const float wh_loss = dwh0 * dwh0 + dwh1 * dwh1;

        // conf-obj term: id_conf degenerates to 0 when max_iou == 0
        const int   id_conf = (max_iou > 0.0f) ? max_id : 0;
        const float sel_c   = id_conf ? o[9] : o[4];
        const float sel_iou = (id_conf == max_id) ? max_iou : 0.0f;
        const float dcf     = sel_c - sel_iou;
        const float c_obj   = dcf * dcf;

        // noobj conf term (both boxes)
        const float dn0 = o[4] - t[4], dn1 = o[9] - t[9];
        const float c_noobj = dn0 * dn0 + dn1 * dn1;

        acc += m ? (5.0f * (xy_loss + wh_loss) + c_obj)
                 : (0.5f * c_noobj);
        // (cls term already accumulated during staging, obj-masked)
    }

    // ---- wave (64-lane) + block reduction ----
#pragma unroll
    for (int off = 32; off > 0; off >>= 1)
        acc += __shfl_down(acc, off);

    __shared__ float wsum[4];
    const int lane = threadIdx.x & 63;
    const int wid  = threadIdx.x >> 6;
    if (lane == 0) wsum[wid] = acc;
    __syncthreads();
    if (threadIdx.x == 0) {
        float bsum = wsum[0] + wsum[1] + wsum[2] + wsum[3];
        atomicAdd(res, bsum * INV_BS_);
    }
}

extern "C" void kernel_launch(void* const* d_in, const int* in_sizes, int n_in,
                              void* d_out, int out_size, void* d_ws, size_t ws_size,
                              hipStream_t stream) {
    const float* outp = (const float*)d_in[0];
    const float* tgtp = (const float*)d_in[1];
    const int*   mask = (const int*)d_in[2];
    float*       res  = (float*)d_out;

    const int ncell = in_sizes[2];        // 8192*7*7 = 401408 (exact /256)

    // d_out is re-poisoned to 0xAA before every replay; zero it on-stream.
    hipMemsetAsync(d_out, 0, sizeof(float), stream);

    const int threads = 256;
    const int blocks  = ncell / threads;  // exact: 1568
    yolo_loss_kernel<<<blocks, threads, 0, stream>>>(outp, tgtp, mask, res);
}

// Round 3
// 122.442 us; speedup vs baseline: 1.1031x; 1.1031x over previous
//
#include <hip/hip_runtime.h>

// YOLO v1 loss, fused reduction — coalesced staging + two-stage reduce.
// Shapes: output/target (8192, 7, 7, 30) f32, grid_mask_obj (8192,7,7) i32.
// Out: scalar f32 loss.
//
// R3 change vs R2: the single contended atomicAdd (1568 blocks -> one f32
// address, serialized RMW chain ~= 44 us) is replaced by per-block partial
// stores into d_ws + a tiny second reduce kernel. Compute/staging identical
// to the verified R2 kernel.

constexpr float CELLW_  = 1.0f / 7.0f;
constexpr float IMG_    = 448.0f;
constexpr float INV_BS_ = 1.0f / 8192.0f;
constexpr int   NCELL_  = 8192 * 7 * 7;   // 401408
constexpr int   NBLK_   = NCELL_ / 256;   // 1568

__global__ __launch_bounds__(256) void yolo_partial_kernel(
    const float* __restrict__ outp, const float* __restrict__ tgtp,
    const int* __restrict__ maskp, float* __restrict__ partial)
{
    __shared__ int   lmask[256];
    __shared__ float lo[256 * 11];
    __shared__ float lt[256 * 11];

    const int tid   = threadIdx.x;
    const int cell0 = blockIdx.x * 256;   // grid exact: 401408 = 1568*256

    lmask[tid] = maskp[cell0 + tid];
    __syncthreads();                      // mask visible to all waves

    const float2* po = reinterpret_cast<const float2*>(outp) + (size_t)cell0 * 15;
    const float2* pt = reinterpret_cast<const float2*>(tgtp) + (size_t)cell0 * 15;

    float acc = 0.0f;

    // Incremental (cell c, channel ch) for dword index d0 = 2*tid + 512*k.
    // Step 512 dwords = 17 cells + 2 channels. ch stays even -> a float2
    // never straddles a cell boundary nor the ch=9/10 regime boundary.
    int c  = (2 * tid) / 30;
    int ch = (2 * tid) - c * 30;

#pragma unroll
    for (int k = 0; k < 15; ++k) {
        const int j = tid + 256 * k;
        float2 vo = po[j];
        float2 vt = pt[j];
        if (ch < 10) {
            // box/conf channels -> LDS (stride 11, gcd(11,32)=1)
            lo[c * 11 + ch]     = vo.x;
            lo[c * 11 + ch + 1] = vo.y;
            lt[c * 11 + ch]     = vt.x;
            lt[c * 11 + ch + 1] = vt.y;
        } else {
            // cls channels: obj-masked SSE, accumulate in-register
            float dx = vo.x - vt.x;
            float dy = vo.y - vt.y;
            acc += lmask[c] ? (dx * dx + dy * dy) : 0.0f;
        }
        ch += 2; c += 17;
        if (ch >= 30) { ch -= 30; c += 1; }
    }
    __syncthreads();

    // ---- per-cell box math (thread tid owns cell cell0+tid) ----
    {
        const float* o = &lo[tid * 11];
        const float* t = &lt[tid * 11];
        const int    m = lmask[tid];

        const int rem = (cell0 + tid) % 49;  // row = rem/7 (y), col = rem%7 (x)
        const float gx = (float)(rem % 7) * CELLW_;
        const float gy = (float)(rem / 7) * CELLW_;

        // target box 0 -> pixel corners
        const float tx = (t[0] * CELLW_ + gx) * IMG_;
        const float ty = (t[1] * CELLW_ + gy) * IMG_;
        const float tw = t[2] * IMG_, th = t[3] * IMG_;
        const float tx1 = tx - tw * 0.5f, tx2 = tx + tw * 0.5f;
        const float ty1 = ty - th * 0.5f, ty2 = ty + th * 0.5f;
        const float area_t = (tx2 - tx1) * (ty2 - ty1);

        float iou[2];
#pragma unroll
        for (int b = 0; b < 2; ++b) {
            float b0 = (b == 0) ? o[0] : o[5];
            float b1 = (b == 0) ? o[1] : o[6];
            float b2 = (b == 0) ? o[2] : o[7];
            float b3 = (b == 0) ? o[3] : o[8];
            float x = (b0 * CELLW_ + gx) * IMG_;
            float y = (b1 * CELLW_ + gy) * IMG_;
            float w = b2 * IMG_, h = b3 * IMG_;
            float x1 = x - w * 0.5f, x2 = x + w * 0.5f;
            float y1 = y - h * 0.5f, y2 = y + h * 0.5f;
            float iw = fmaxf(fminf(x2, tx2) - fmaxf(x1, tx1), 0.0f);
            float ih = fmaxf(fminf(y2, ty2) - fmaxf(y1, ty1), 0.0f);
            float inter = iw * ih;
            float area_o = (x2 - x1) * (y2 - y1);
            iou[b] = inter / (area_o + area_t - inter);
        }

        const int   max_id  = (iou[1] > iou[0]) ? 1 : 0;   // argmax, tie->first
        const float max_iou = fmaxf(iou[0], iou[1]);

        // selected box (static indices via ternaries — no runtime indexing)
        const float so0 = max_id ? o[5] : o[0];
        const float so1 = max_id ? o[6] : o[1];
        const float so2 = max_id ? o[7] : o[2];
        const float so3 = max_id ? o[8] : o[3];
        const float st0 = max_id ? t[5] : t[0];
        const float st1 = max_id ? t[6] : t[1];
        const float st2 = max_id ? t[7] : t[2];
        const float st3 = max_id ? t[8] : t[3];

        const float dxy0 = so0 - st0, dxy1 = so1 - st1;
        const float xy_loss = dxy0 * dxy0 + dxy1 * dxy1;

        const float dwh0 = sqrtf(so2) - sqrtf(st2);
        const float dwh1 = sqrtf(so3) - sqrtf(st3);
        const float wh_loss = dwh0 * dwh0 + dwh1 * dwh1;

        // conf-obj term: id_conf degenerates to 0 when max_iou == 0
        const int   id_conf = (max_iou > 0.0f) ? max_id : 0;
        const float sel_c   = id_conf ? o[9] : o[4];
        const float sel_iou = (id_conf == max_id) ? max_iou : 0.0f;
        const float dcf     = sel_c - sel_iou;
        const float c_obj   = dcf * dcf;

        // noobj conf term (both boxes)
        const float dn0 = o[4] - t[4], dn1 = o[9] - t[9];
        const float c_noobj = dn0 * dn0 + dn1 * dn1;

        acc += m ? (5.0f * (xy_loss + wh_loss) + c_obj)
                 : (0.5f * c_noobj);
        // (cls term already accumulated during staging, obj-masked)
    }

    // ---- wave (64-lane) + block reduction, plain store (NO atomic) ----
#pragma unroll
    for (int off = 32; off > 0; off >>= 1)
        acc += __shfl_down(acc, off);

    __shared__ float wsum[4];
    const int lane = threadIdx.x & 63;
    const int wid  = threadIdx.x >> 6;
    if (lane == 0) wsum[wid] = acc;
    __syncthreads();
    if (threadIdx.x == 0)
        partial[blockIdx.x] = wsum[0] + wsum[1] + wsum[2] + wsum[3];
}

__global__ __launch_bounds__(256) void yolo_reduce_kernel(
    const float* __restrict__ partial, float* __restrict__ out)
{
    float a = 0.0f;
    for (int i = threadIdx.x; i < NBLK_; i += 256)
        a += partial[i];

#pragma unroll
    for (int off = 32; off > 0; off >>= 1)
        a += __shfl_down(a, off);

    __shared__ float wsum[4];
    const int lane = threadIdx.x & 63;
    const int wid  = threadIdx.x >> 6;
    if (lane == 0) wsum[wid] = a;
    __syncthreads();
    if (threadIdx.x == 0)
        out[0] = (wsum[0] + wsum[1] + wsum[2] + wsum[3]) * INV_BS_;
}

extern "C" void kernel_launch(void* const* d_in, const int* in_sizes, int n_in,
                              void* d_out, int out_size, void* d_ws, size_t ws_size,
                              hipStream_t stream) {
    const float* outp = (const float*)d_in[0];
    const float* tgtp = (const float*)d_in[1];
    const int*   mask = (const int*)d_in[2];
    float*       res  = (float*)d_out;
    float*       part = (float*)d_ws;     // 1568 floats of scratch

    const int ncell = in_sizes[2];        // 401408
    const int blocks = ncell / 256;       // 1568 exact

    yolo_partial_kernel<<<blocks, 256, 0, stream>>>(outp, tgtp, mask, part);
    yolo_reduce_kernel<<<1, 256, 0, stream>>>(part, res);
}

// Round 4
// 115.129 us; speedup vs baseline: 1.1732x; 1.0635x over previous
//
#include <hip/hip_runtime.h>

// YOLO v1 loss, fused reduction — coalesced staging + two-stage reduce.
// Shapes: output/target (8192, 7, 7, 30) f32, grid_mask_obj (8192,7,7) i32.
// Out: scalar f32 loss.
//
// R4 change vs R3: load phase split from consume phase. All 30 float2 loads
// are issued into statically-indexed register arrays (vo[15]/vt[15]) before
// any consumption, so they overlap in flight (R3's fused loop left VGPR=40
// and serialized ~1 load at a time -> latency-bound at 2.3 TB/s blended).
// Scatter/accumulate loop and per-cell math identical to verified R3.

constexpr float CELLW_  = 1.0f / 7.0f;
constexpr float IMG_    = 448.0f;
constexpr float INV_BS_ = 1.0f / 8192.0f;
constexpr int   NCELL_  = 8192 * 7 * 7;   // 401408
constexpr int   NBLK_   = NCELL_ / 256;   // 1568

__global__ __launch_bounds__(256) void yolo_partial_kernel(
    const float* __restrict__ outp, const float* __restrict__ tgtp,
    const int* __restrict__ maskp, float* __restrict__ partial)
{
    __shared__ int   lmask[256];
    __shared__ float lo[256 * 11];
    __shared__ float lt[256 * 11];

    const int tid   = threadIdx.x;
    const int cell0 = blockIdx.x * 256;   // grid exact: 401408 = 1568*256

    lmask[tid] = maskp[cell0 + tid];
    __syncthreads();                      // mask visible before the acc loop

    const float2* po = reinterpret_cast<const float2*>(outp) + (size_t)cell0 * 15;
    const float2* pt = reinterpret_cast<const float2*>(tgtp) + (size_t)cell0 * 15;

    // ---- load phase: 30 independent 8B loads, all in flight ----
    float2 vo[15], vt[15];
#pragma unroll
    for (int k = 0; k < 15; ++k) vo[k] = po[tid + 256 * k];
#pragma unroll
    for (int k = 0; k < 15; ++k) vt[k] = pt[tid + 256 * k];

    float acc = 0.0f;

    // ---- consume phase: scatter box/conf to LDS, fold cls SSE ----
    // Incremental (cell c, channel ch) for dword index d0 = 2*tid + 512*k.
    // Step 512 dwords = 17 cells + 2 channels. ch stays even -> a float2
    // never straddles a cell boundary nor the ch=9/10 regime boundary.
    int c  = (2 * tid) / 30;
    int ch = (2 * tid) - c * 30;

#pragma unroll
    for (int k = 0; k < 15; ++k) {
        float2 o2 = vo[k];
        float2 t2 = vt[k];
        if (ch < 10) {
            // box/conf channels -> LDS (stride 11, gcd(11,32)=1)
            lo[c * 11 + ch]     = o2.x;
            lo[c * 11 + ch + 1] = o2.y;
            lt[c * 11 + ch]     = t2.x;
            lt[c * 11 + ch + 1] = t2.y;
        } else {
            // cls channels: obj-masked SSE, accumulate in-register
            float dx = o2.x - t2.x;
            float dy = o2.y - t2.y;
            acc += lmask[c] ? (dx * dx + dy * dy) : 0.0f;
        }
        ch += 2; c += 17;
        if (ch >= 30) { ch -= 30; c += 1; }
    }
    __syncthreads();

    // ---- per-cell box math (thread tid owns cell cell0+tid) ----
    {
        const float* o = &lo[tid * 11];
        const float* t = &lt[tid * 11];
        const int    m = lmask[tid];

        const int rem = (cell0 + tid) % 49;  // row = rem/7 (y), col = rem%7 (x)
        const float gx = (float)(rem % 7) * CELLW_;
        const float gy = (float)(rem / 7) * CELLW_;

        // target box 0 -> pixel corners
        const float tx = (t[0] * CELLW_ + gx) * IMG_;
        const float ty = (t[1] * CELLW_ + gy) * IMG_;
        const float tw = t[2] * IMG_, th = t[3] * IMG_;
        const float tx1 = tx - tw * 0.5f, tx2 = tx + tw * 0.5f;
        const float ty1 = ty - th * 0.5f, ty2 = ty + th * 0.5f;
        const float area_t = (tx2 - tx1) * (ty2 - ty1);

        float iou[2];
#pragma unroll
        for (int b = 0; b < 2; ++b) {
            float b0 = (b == 0) ? o[0] : o[5];
            float b1 = (b == 0) ? o[1] : o[6];
            float b2 = (b == 0) ? o[2] : o[7];
            float b3 = (b == 0) ? o[3] : o[8];
            float x = (b0 * CELLW_ + gx) * IMG_;
            float y = (b1 * CELLW_ + gy) * IMG_;
            float w = b2 * IMG_, h = b3 * IMG_;
            float x1 = x - w * 0.5f, x2 = x + w * 0.5f;
            float y1 = y - h * 0.5f, y2 = y + h * 0.5f;
            float iw = fmaxf(fminf(x2, tx2) - fmaxf(x1, tx1), 0.0f);
            float ih = fmaxf(fminf(y2, ty2) - fmaxf(y1, ty1), 0.0f);
            float inter = iw * ih;
            float area_o = (x2 - x1) * (y2 - y1);
            iou[b] = inter / (area_o + area_t - inter);
        }

        const int   max_id  = (iou[1] > iou[0]) ? 1 : 0;   // argmax, tie->first
        const float max_iou = fmaxf(iou[0], iou[1]);

        // selected box (static indices via ternaries — no runtime indexing)
        const float so0 = max_id ? o[5] : o[0];
        const float so1 = max_id ? o[6] : o[1];
        const float so2 = max_id ? o[7] : o[2];
        const float so3 = max_id ? o[8] : o[3];
        const float st0 = max_id ? t[5] : t[0];
        const float st1 = max_id ? t[6] : t[1];
        const float st2 = max_id ? t[7] : t[2];
        const float st3 = max_id ? t[8] : t[3];

        const float dxy0 = so0 - st0, dxy1 = so1 - st1;
        const float xy_loss = dxy0 * dxy0 + dxy1 * dxy1;

        const float dwh0 = sqrtf(so2) - sqrtf(st2);
        const float dwh1 = sqrtf(so3) - sqrtf(st3);
        const float wh_loss = dwh0 * dwh0 + dwh1 * dwh1;

        // conf-obj term: id_conf degenerates to 0 when max_iou == 0
        const int   id_conf = (max_iou > 0.0f) ? max_id : 0;
        const float sel_c   = id_conf ? o[9] : o[4];
        const float sel_iou = (id_conf == max_id) ? max_iou : 0.0f;
        const float dcf     = sel_c - sel_iou;
        const float c_obj   = dcf * dcf;

        // noobj conf term (both boxes)
        const float dn0 = o[4] - t[4], dn1 = o[9] - t[9];
        const float c_noobj = dn0 * dn0 + dn1 * dn1;

        acc += m ? (5.0f * (xy_loss + wh_loss) + c_obj)
                 : (0.5f * c_noobj);
        // (cls term already accumulated during staging, obj-masked)
    }

    // ---- wave (64-lane) + block reduction, plain store (NO atomic) ----
#pragma unroll
    for (int off = 32; off > 0; off >>= 1)
        acc += __shfl_down(acc, off);

    __shared__ float wsum[4];
    const int lane = threadIdx.x & 63;
    const int wid  = threadIdx.x >> 6;
    if (lane == 0) wsum[wid] = acc;
    __syncthreads();
    if (threadIdx.x == 0)
        partial[blockIdx.x] = wsum[0] + wsum[1] + wsum[2] + wsum[3];
}

__global__ __launch_bounds__(256) void yolo_reduce_kernel(
    const float* __restrict__ partial, float* __restrict__ out)
{
    float a = 0.0f;
    for (int i = threadIdx.x; i < NBLK_; i += 256)
        a += partial[i];

#pragma unroll
    for (int off = 32; off > 0; off >>= 1)
        a += __shfl_down(a, off);

    __shared__ float wsum[4];
    const int lane = threadIdx.x & 63;
    const int wid  = threadIdx.x >> 6;
    if (lane == 0) wsum[wid] = a;
    __syncthreads();
    if (threadIdx.x == 0)
        out[0] = (wsum[0] + wsum[1] + wsum[2] + wsum[3]) * INV_BS_;
}

extern "C" void kernel_launch(void* const* d_in, const int* in_sizes, int n_in,
                              void* d_out, int out_size, void* d_ws, size_t ws_size,
                              hipStream_t stream) {
    const float* outp = (const float*)d_in[0];
    const float* tgtp = (const float*)d_in[1];
    const int*   mask = (const int*)d_in[2];
    float*       res  = (float*)d_out;
    float*       part = (float*)d_ws;     // 1568 floats of scratch

    const int ncell = in_sizes[2];        // 401408
    const int blocks = ncell / 256;       // 1568 exact

    yolo_partial_kernel<<<blocks, 256, 0, stream>>>(outp, tgtp, mask, part);
    yolo_reduce_kernel<<<1, 256, 0, stream>>>(part, res);
}